// Round 3
// baseline (230.143 us; speedup 1.0000x reference)
//
#include <hip/hip_runtime.h>
#include <hip/hip_bf16.h>
#include <math.h>

#define NN 1024

typedef short bf16x8 __attribute__((ext_vector_type(8)));
typedef float f32x4 __attribute__((ext_vector_type(4)));

__device__ __forceinline__ unsigned rne_u(float x) {
    unsigned u = __float_as_uint(x);
    return u + 0x7fffu + ((u >> 16) & 1u);
}
__device__ __forceinline__ float bf16_up_bits(unsigned hi16) {
    return __uint_as_float(hi16 << 16);
}
__device__ __forceinline__ unsigned pair_pack(float a, float b) {   // a->low, b->high, RNE
    return (rne_u(a) >> 16) | (rne_u(b) & 0xffff0000u);
}
// packed fp32x2 -> bf16x2 via HIP intrinsic (v_cvt_pk_bf16_f32 on gfx950)
__device__ __forceinline__ unsigned pack2(float a, float b) {
    __hip_bfloat162 h = __float22bfloat162_rn(make_float2(a, b));
    unsigned u;
    __builtin_memcpy(&u, &h, 4);
    return u;   // little-endian: x (=a) in low 16
}

union U16 { uint4 u; bf16x8 v; };
union P4 { unsigned w[4]; bf16x8 v; };

// h1 fragment: relu(x + c) -> bf16 RNE, element e at k = q*8+e
__device__ __forceinline__ bf16x8 mk_frag(float4 x0, float4 x1, float4 c0, float4 c1) {
    P4 u;
    u.w[0] = pack2(fmaxf(x0.x + c0.x, 0.f), fmaxf(x0.y + c0.y, 0.f));
    u.w[1] = pack2(fmaxf(x0.z + c0.z, 0.f), fmaxf(x0.w + c0.w, 0.f));
    u.w[2] = pack2(fmaxf(x1.x + c1.x, 0.f), fmaxf(x1.y + c1.y, 0.f));
    u.w[3] = pack2(fmaxf(x1.z + c1.z, 0.f), fmaxf(x1.w + c1.w, 0.f));
    return u.v;
}

// ---- prep: blocks [0,512): A'=z_c@W1c+b1, B=z_d@W1d (fp32 exact).
//            blocks [512,514): W2 -> MFMA frag layout (hi+lo bf16), zero Srow/accum/done.
__global__ void prep_kernel(const float* __restrict__ z_c, const float* __restrict__ z_d,
                            const float* __restrict__ W1, const float* __restrict__ b1,
                            const float* __restrict__ W2,
                            float* __restrict__ Ap, float* __restrict__ Bp,
                            uint4* __restrict__ W2hi, uint4* __restrict__ W2lo,
                            float* __restrict__ Srow, float* __restrict__ accum) {
    if (blockIdx.x < 512) {
        int t = blockIdx.x * 256 + threadIdx.x;
        if (t == 0) { accum[0] = 0.f; accum[1] = 0.f; accum[2] = 0.f; accum[3] = 0.f; }
        int sel = t >> 16;            // 0 -> A', 1 -> B
        int idx = t & 0xffff;
        int n = idx >> 6, h = idx & 63;
        const float* z = (sel ? z_d : z_c) + n * 64;
        const float* w = W1 + (sel ? 4096 : 0) + h;   // W1 (128,64) row-major
        float a0 = sel ? 0.f : b1[h], a1 = 0.f;       // 2 chains to break FMA latency
        #pragma unroll
        for (int k = 0; k < 64; k += 2) {
            a0 = fmaf(z[k],     w[k * 64],      a0);
            a1 = fmaf(z[k + 1], w[(k + 1) * 64], a1);
        }
        (sel ? Bp : Ap)[idx] = a0 + a1;
    } else {
        int tt = (blockIdx.x - 512) * 256 + threadIdx.x;   // 0..511
        Srow[tt] = 0.f; Srow[tt + 512] = 0.f;
        int f = tt >> 6, lane = tt & 63;                   // f = s*4 + t
        int s = f >> 2, t4 = f & 3, q = lane >> 4, l15 = lane & 15;
        int n = t4 * 16 + l15;
        unsigned hi[4], lo[4];
        #pragma unroll
        for (int p = 0; p < 4; ++p) {
            int k = s * 32 + q * 8 + 2 * p;
            float w0 = W2[k * 64 + n], w1 = W2[(k + 1) * 64 + n];
            unsigned h0 = rne_u(w0) >> 16, h1 = rne_u(w1) >> 16;
            hi[p] = h0 | (h1 << 16);
            lo[p] = pair_pack(w0 - bf16_up_bits(h0), w1 - bf16_up_bits(h1));
        }
        W2hi[f * 64 + lane] = make_uint4(hi[0], hi[1], hi[2], hi[3]);
        W2lo[f * 64 + lane] = make_uint4(lo[0], lo[1], lo[2], lo[3]);
    }
}

// ---- main: block = (i, half). 2048 blocks x 256 thr; each wave 8 j-tiles of 16.
// Operand-swapped MFMA: D = W2^T-frag (as A) x h1-frag (as B)  => acc[t][r] =
// h2pre[j = jbase+l15][h = t*16 + q*4 + r].  T1 reduction needs only 2 shfls.
// Last block to finish folds in the lse-combine + final bound (saves 2 graph nodes).
__global__ void __launch_bounds__(256)
main_kernel(const float* __restrict__ Ap, const float* __restrict__ Bp,
            const uint4* __restrict__ W2hi, const uint4* __restrict__ W2lo,
            const float* __restrict__ b2, const float* __restrict__ Wo,
            float* __restrict__ Srow, float* __restrict__ accum,
            unsigned* __restrict__ done, float* __restrict__ out) {
    const int i    = blockIdx.x >> 1;
    const int half = blockIdx.x & 1;
    const int lane = threadIdx.x & 63;
    const int wave = threadIdx.x >> 6;
    const int l15  = lane & 15;
    const int q    = lane >> 4;

    // W2 fragments (identical bits serve as A-operand; lane mapping is the same)
    bf16x8 whi[2][4], wlo[2][4];
    #pragma unroll
    for (int f = 0; f < 8; ++f) {
        U16 a, b;
        a.u = W2hi[f * 64 + lane];
        b.u = W2lo[f * 64 + lane];
        whi[f >> 2][f & 3] = a.v;
        wlo[f >> 2][f & 3] = b.v;
    }

    // B_i per-lane slice, k = s*32 + q*8 + e
    const float* bpr = Bp + i * 64 + q * 8;
    float4 c00 = *(const float4*)(bpr);
    float4 c01 = *(const float4*)(bpr + 4);
    float4 c10 = *(const float4*)(bpr + 32);
    float4 c11 = *(const float4*)(bpr + 36);

    // b2 / Wo per-lane: element (t,r) is h = t*16 + q*4 + r
    float b2v[4][4], wov[4][4];
    #pragma unroll
    for (int t = 0; t < 4; ++t) {
        float4 bt = *(const float4*)(b2 + t * 16 + q * 4);
        float4 wt = *(const float4*)(Wo + t * 16 + q * 4);
        b2v[t][0] = bt.x; b2v[t][1] = bt.y; b2v[t][2] = bt.z; b2v[t][3] = bt.w;
        wov[t][0] = wt.x; wov[t][1] = wt.y; wov[t][2] = wt.z; wov[t][3] = wt.w;
    }

    const int jwbase = half * 512 + wave * 128;
    const float* ap = Ap + (jwbase + l15) * 64 + q * 8;
    float4 x00 = *(const float4*)(ap);
    float4 x01 = *(const float4*)(ap + 4);
    float4 x10 = *(const float4*)(ap + 32);
    float4 x11 = *(const float4*)(ap + 36);

    float sacc = 0.f;

    #pragma unroll
    for (int tile = 0; tile < 8; ++tile) {
        bf16x8 a0 = mk_frag(x00, x01, c00, c01);   // k 0..31
        bf16x8 a1 = mk_frag(x10, x11, c10, c11);   // k 32..63
        if (tile < 7) {                             // prefetch next tile
            ap += 16 * 64;
            x00 = *(const float4*)(ap);
            x01 = *(const float4*)(ap + 4);
            x10 = *(const float4*)(ap + 32);
            x11 = *(const float4*)(ap + 36);
        }

        f32x4 acc[4];
        #pragma unroll
        for (int t = 0; t < 4; ++t) acc[t] = (f32x4){0.f, 0.f, 0.f, 0.f};
        #pragma unroll
        for (int t = 0; t < 4; ++t) {
            acc[t] = __builtin_amdgcn_mfma_f32_16x16x32_bf16(whi[0][t], a0, acc[t], 0, 0, 0);
            acc[t] = __builtin_amdgcn_mfma_f32_16x16x32_bf16(whi[1][t], a1, acc[t], 0, 0, 0);
            acc[t] = __builtin_amdgcn_mfma_f32_16x16x32_bf16(wlo[0][t], a0, acc[t], 0, 0, 0);
            acc[t] = __builtin_amdgcn_mfma_f32_16x16x32_bf16(wlo[1][t], a1, acc[t], 0, 0, 0);
        }

        // T1[j] = sum_h relu(h2pre[j,h] + b2[h]) * Wo[h]; per lane h = t*16+q*4+r
        float psum = 0.f;
        #pragma unroll
        for (int t = 0; t < 4; ++t)
            #pragma unroll
            for (int r = 0; r < 4; ++r)
                psum = fmaf(fmaxf(acc[t][r] + b2v[t][r], 0.f), wov[t][r], psum);
        psum += __shfl_xor(psum, 16);
        psum += __shfl_xor(psum, 32);   // full T1[j], replicated across the 4 q-lanes

        const int j = jwbase + tile * 16 + l15;
        if (j == i && q == 0) atomicAdd(&accum[0], psum);   // T0[i] (diagonal), exact once
        sacc += __expf(psum);                                // 4x q-replicated
    }

    #pragma unroll
    for (int off = 1; off < 64; off <<= 1) sacc += __shfl_xor(sacc, off);
    if (lane == 0) atomicAdd(&Srow[i], sacc);   // Srow[i] accumulates 4*sum_j exp(T1[i,j])

    // ---- last-block combine (replaces 2 kernel launches)
    __threadfence();
    __syncthreads();
    __shared__ unsigned isLast;
    if (threadIdx.x == 0)
        isLast = (atomicAdd(done, 1u) == 2047u) ? 1u : 0u;
    __syncthreads();
    if (isLast) {
        float part = 0.f;
        #pragma unroll
        for (int rep = 0; rep < 4; ++rep) {
            int idx = rep * 256 + threadIdx.x;
            float s = __hip_atomic_load(&Srow[idx], __ATOMIC_RELAXED, __HIP_MEMORY_SCOPE_AGENT);
            part += logf(s);
        }
        #pragma unroll
        for (int off = 1; off < 64; off <<= 1) part += __shfl_xor(part, off);
        __shared__ float sp[4];
        if (lane == 0) sp[wave] = part;
        __syncthreads();
        if (threadIdx.x == 0) {
            float lsum = sp[0] + sp[1] + sp[2] + sp[3];   // sum_i log(4 * sum_j exp)
            float t0 = __hip_atomic_load(&accum[0], __ATOMIC_RELAXED, __HIP_MEMORY_SCOPE_AGENT);
            // bound = T0/N - (mean(log Srow) - ln4 - lnN) ; ln4 + ln1024 = ln4096
            out[0] = t0 * (1.0f / 1024.0f) - lsum * (1.0f / 1024.0f)
                   + 8.3177661667193446f;
        }
    }
}

extern "C" void kernel_launch(void* const* d_in, const int* in_sizes, int n_in,
                              void* d_out, int out_size, void* d_ws, size_t ws_size,
                              hipStream_t stream) {
    const float* z_c = (const float*)d_in[0];
    const float* z_d = (const float*)d_in[1];
    const float* W1  = (const float*)d_in[2];
    const float* b1  = (const float*)d_in[3];
    const float* W2  = (const float*)d_in[4];
    const float* b2  = (const float*)d_in[5];
    const float* Wo  = (const float*)d_in[6];
    // d_in[7] = bo: shifts T0.mean and every LSE equally -> cancels; omitted.
    float* out   = (float*)d_out;

    float* accum = (float*)d_ws;                 // [0]=sum T0, [2]=done ctr
    unsigned* done = (unsigned*)(accum + 2);
    float* Ap    = accum + 16;                   // 65536 fp32
    float* Bp    = Ap + NN * 64;                 // 65536 fp32
    uint4* W2hi  = (uint4*)(Bp + NN * 64);       // 512 uint4
    uint4* W2lo  = W2hi + 512;                   // 512 uint4
    float* Srow  = (float*)(W2lo + 512);         // 1024 fp32

    prep_kernel<<<514, 256, 0, stream>>>(z_c, z_d, W1, b1, W2, Ap, Bp, W2hi, W2lo, Srow, accum);
    main_kernel<<<2048, 256, 0, stream>>>(Ap, Bp, W2hi, W2lo, b2, Wo, Srow, accum, done, out);
}

// Round 4
// 126.108 us; speedup vs baseline: 1.8250x; 1.8250x over previous
//
#include <hip/hip_runtime.h>
#include <hip/hip_bf16.h>
#include <math.h>

#define NN 1024

typedef short bf16x8 __attribute__((ext_vector_type(8)));
typedef float f32x4 __attribute__((ext_vector_type(4)));

__device__ __forceinline__ unsigned rne_u(float x) {
    unsigned u = __float_as_uint(x);
    return u + 0x7fffu + ((u >> 16) & 1u);
}
__device__ __forceinline__ float bf16_up_bits(unsigned hi16) {
    return __uint_as_float(hi16 << 16);
}
__device__ __forceinline__ unsigned pair_pack(float a, float b) {   // a->low, b->high, RNE
    return (rne_u(a) >> 16) | (rne_u(b) & 0xffff0000u);
}
// packed fp32x2 -> bf16x2 (v_cvt_pk_bf16_f32 on gfx950)
__device__ __forceinline__ unsigned pack2(float a, float b) {
    __hip_bfloat162 h = __float22bfloat162_rn(make_float2(a, b));
    unsigned u;
    __builtin_memcpy(&u, &h, 4);
    return u;
}

union U16 { uint4 u; bf16x8 v; };
union P4 { unsigned w[4]; bf16x8 v; };

// h1 fragment: relu(x + c) -> bf16 RNE, element e at k = q*8+e
__device__ __forceinline__ bf16x8 mk_frag(float4 x0, float4 x1, float4 c0, float4 c1) {
    P4 u;
    u.w[0] = pack2(fmaxf(x0.x + c0.x, 0.f), fmaxf(x0.y + c0.y, 0.f));
    u.w[1] = pack2(fmaxf(x0.z + c0.z, 0.f), fmaxf(x0.w + c0.w, 0.f));
    u.w[2] = pack2(fmaxf(x1.x + c1.x, 0.f), fmaxf(x1.y + c1.y, 0.f));
    u.w[3] = pack2(fmaxf(x1.z + c1.z, 0.f), fmaxf(x1.w + c1.w, 0.f));
    return u.v;
}

// ---- prep: blocks [0,512): A'=z_c@W1c+b1, B=z_d@W1d (fp32 exact).
//            blocks [512,514): W2 -> MFMA frag layout (hi+lo bf16), zero Srow/accum.
__global__ void prep_kernel(const float* __restrict__ z_c, const float* __restrict__ z_d,
                            const float* __restrict__ W1, const float* __restrict__ b1,
                            const float* __restrict__ W2,
                            float* __restrict__ Ap, float* __restrict__ Bp,
                            uint4* __restrict__ W2hi, uint4* __restrict__ W2lo,
                            float* __restrict__ Srow, float* __restrict__ accum) {
    if (blockIdx.x < 512) {
        int t = blockIdx.x * 256 + threadIdx.x;
        if (t == 0) { accum[0] = 0.f; accum[1] = 0.f; }
        int sel = t >> 16;            // 0 -> A', 1 -> B
        int idx = t & 0xffff;
        int n = idx >> 6, h = idx & 63;
        const float* z = (sel ? z_d : z_c) + n * 64;
        const float* w = W1 + (sel ? 4096 : 0) + h;   // W1 (128,64) row-major
        float a0 = sel ? 0.f : b1[h], a1 = 0.f;
        #pragma unroll
        for (int k = 0; k < 64; k += 2) {
            a0 = fmaf(z[k],     w[k * 64],       a0);
            a1 = fmaf(z[k + 1], w[(k + 1) * 64], a1);
        }
        (sel ? Bp : Ap)[idx] = a0 + a1;
    } else {
        int tt = (blockIdx.x - 512) * 256 + threadIdx.x;   // 0..511
        Srow[tt] = 0.f; Srow[tt + 512] = 0.f;
        int f = tt >> 6, lane = tt & 63;                   // f = s*4 + t
        int s = f >> 2, t4 = f & 3, q = lane >> 4, l15 = lane & 15;
        int n = t4 * 16 + l15;
        unsigned hi[4], lo[4];
        #pragma unroll
        for (int p = 0; p < 4; ++p) {
            int k = s * 32 + q * 8 + 2 * p;
            float w0 = W2[k * 64 + n], w1 = W2[(k + 1) * 64 + n];
            unsigned h0 = rne_u(w0) >> 16, h1 = rne_u(w1) >> 16;
            hi[p] = h0 | (h1 << 16);
            lo[p] = pair_pack(w0 - bf16_up_bits(h0), w1 - bf16_up_bits(h1));
        }
        W2hi[f * 64 + lane] = make_uint4(hi[0], hi[1], hi[2], hi[3]);
        W2lo[f * 64 + lane] = make_uint4(lo[0], lo[1], lo[2], lo[3]);
    }
}

// ---- main: block = (i, half). 2048 blocks x 256 thr; each wave 8 j-tiles of 16.
// Operand-swapped MFMA: D = W2-frag (as A) x h1-frag (as B) => acc[t][r] =
// h2pre[j = jbase+l15][h = t*16 + q*4 + r], with acc INITIALIZED to b2 (folds the add).
// No fence, no cross-block sync: Srow partials via one atomic per block.
__global__ void __launch_bounds__(256, 3)
main_kernel(const float* __restrict__ Ap, const float* __restrict__ Bp,
            const uint4* __restrict__ W2hi, const uint4* __restrict__ W2lo,
            const float* __restrict__ b2, const float* __restrict__ Wo,
            float* __restrict__ Srow, float* __restrict__ accum) {
    const int i    = blockIdx.x >> 1;
    const int half = blockIdx.x & 1;
    const int lane = threadIdx.x & 63;
    const int wave = threadIdx.x >> 6;
    const int l15  = lane & 15;
    const int q    = lane >> 4;

    // W2 fragments: 16 coalesced dwordx4 loads (precomputed layout, L2-hot)
    bf16x8 whi[2][4], wlo[2][4];
    #pragma unroll
    for (int f = 0; f < 8; ++f) {
        U16 a, b;
        a.u = W2hi[f * 64 + lane];
        b.u = W2lo[f * 64 + lane];
        whi[f >> 2][f & 3] = a.v;
        wlo[f >> 2][f & 3] = b.v;
    }

    // B_i per-lane slice, k = s*32 + q*8 + e
    const float* bpr = Bp + i * 64 + q * 8;
    float4 c00 = *(const float4*)(bpr);
    float4 c01 = *(const float4*)(bpr + 4);
    float4 c10 = *(const float4*)(bpr + 32);
    float4 c11 = *(const float4*)(bpr + 36);

    // b2 / Wo per-lane: element (t,r) is h = t*16 + q*4 + r
    f32x4 b2v[4];
    float wov[4][4];
    #pragma unroll
    for (int t = 0; t < 4; ++t) {
        float4 bt = *(const float4*)(b2 + t * 16 + q * 4);
        float4 wt = *(const float4*)(Wo + t * 16 + q * 4);
        b2v[t] = (f32x4){bt.x, bt.y, bt.z, bt.w};
        wov[t][0] = wt.x; wov[t][1] = wt.y; wov[t][2] = wt.z; wov[t][3] = wt.w;
    }

    const int jwbase = half * 512 + wave * 128;
    const float* ap = Ap + (jwbase + l15) * 64 + q * 8;
    float4 x00 = *(const float4*)(ap);
    float4 x01 = *(const float4*)(ap + 4);
    float4 x10 = *(const float4*)(ap + 32);
    float4 x11 = *(const float4*)(ap + 36);

    float sacc = 0.f;

    #pragma unroll
    for (int tile = 0; tile < 8; ++tile) {
        bf16x8 a0 = mk_frag(x00, x01, c00, c01);   // k 0..31
        bf16x8 a1 = mk_frag(x10, x11, c10, c11);   // k 32..63
        if (tile < 7) {                             // prefetch next tile
            ap += 16 * 64;
            x00 = *(const float4*)(ap);
            x01 = *(const float4*)(ap + 4);
            x10 = *(const float4*)(ap + 32);
            x11 = *(const float4*)(ap + 36);
        }

        f32x4 acc[4];
        #pragma unroll
        for (int t = 0; t < 4; ++t) acc[t] = b2v[t];   // acc starts at b2: h2pre+b2 free
        #pragma unroll
        for (int t = 0; t < 4; ++t) {
            acc[t] = __builtin_amdgcn_mfma_f32_16x16x32_bf16(whi[0][t], a0, acc[t], 0, 0, 0);
            acc[t] = __builtin_amdgcn_mfma_f32_16x16x32_bf16(whi[1][t], a1, acc[t], 0, 0, 0);
            acc[t] = __builtin_amdgcn_mfma_f32_16x16x32_bf16(wlo[0][t], a0, acc[t], 0, 0, 0);
            acc[t] = __builtin_amdgcn_mfma_f32_16x16x32_bf16(wlo[1][t], a1, acc[t], 0, 0, 0);
        }

        // T1[j] = sum_h relu(acc[j,h]) * Wo[h]; per lane h = t*16+q*4+r
        float psum = 0.f;
        #pragma unroll
        for (int t = 0; t < 4; ++t)
            #pragma unroll
            for (int r = 0; r < 4; ++r)
                psum = fmaf(fmaxf(acc[t][r], 0.f), wov[t][r], psum);
        psum += __shfl_xor(psum, 16);
        psum += __shfl_xor(psum, 32);   // full T1[j], replicated across the 4 q-groups

        const int j = jwbase + tile * 16 + l15;
        if (j == i && q == 0) atomicAdd(&accum[0], psum);   // T0[i] diagonal, exact once
        sacc += __expf(psum);                                // 4x q-replicated
    }

    #pragma unroll
    for (int off = 1; off < 16; off <<= 1) sacc += __shfl_xor(sacc, off);
    // lanes replicate in groups; reduce across l15 then q already included via 16/32 shfls below
    sacc += __shfl_xor(sacc, 16);
    sacc += __shfl_xor(sacc, 32);
    __shared__ float sS[4];
    if (lane == 0) sS[wave] = sacc;
    __syncthreads();
    if (threadIdx.x == 0)
        atomicAdd(&Srow[i], sS[0] + sS[1] + sS[2] + sS[3]);   // = 4 * sum_j exp (partial)
}

// ---- combine: lse_i = log(Srow[i]) (the /4 replication folds into the constant)
__global__ void combine_kernel(const float* __restrict__ Srow, float* __restrict__ accum) {
    int i = blockIdx.x * 256 + threadIdx.x;
    float lse = logf(Srow[i]);
    #pragma unroll
    for (int off = 1; off < 64; off <<= 1) lse += __shfl_xor(lse, off);
    if ((threadIdx.x & 63) == 0) atomicAdd(&accum[1], lse);
}

// ---- finish: bound = T0/N - (mean(log Srow) - ln4 - lnN);  ln4 + ln1024 = ln4096
__global__ void finish_kernel(const float* __restrict__ accum, float* __restrict__ out) {
    out[0] = accum[0] * (1.0f / 1024.0f) - accum[1] * (1.0f / 1024.0f)
           + 8.3177661667193446f;
}

extern "C" void kernel_launch(void* const* d_in, const int* in_sizes, int n_in,
                              void* d_out, int out_size, void* d_ws, size_t ws_size,
                              hipStream_t stream) {
    const float* z_c = (const float*)d_in[0];
    const float* z_d = (const float*)d_in[1];
    const float* W1  = (const float*)d_in[2];
    const float* b1  = (const float*)d_in[3];
    const float* W2  = (const float*)d_in[4];
    const float* b2  = (const float*)d_in[5];
    const float* Wo  = (const float*)d_in[6];
    // d_in[7] = bo: shifts T0.mean and every LSE equally -> cancels; omitted.
    float* out   = (float*)d_out;

    float* accum = (float*)d_ws;                 // [0]=sum T0, [1]=sum log Srow
    float* Ap    = accum + 16;                   // 65536 fp32
    float* Bp    = Ap + NN * 64;                 // 65536 fp32
    uint4* W2hi  = (uint4*)(Bp + NN * 64);       // 512 uint4
    uint4* W2lo  = W2hi + 512;                   // 512 uint4
    float* Srow  = (float*)(W2lo + 512);         // 1024 fp32

    prep_kernel<<<514, 256, 0, stream>>>(z_c, z_d, W1, b1, W2, Ap, Bp, W2hi, W2lo, Srow, accum);
    main_kernel<<<2048, 256, 0, stream>>>(Ap, Bp, W2hi, W2lo, b2, Wo, Srow, accum);
    combine_kernel<<<4, 256, 0, stream>>>(Srow, accum);
    finish_kernel<<<1, 1, 0, stream>>>(accum, out);
}